// Round 1
// baseline (254.200 us; speedup 1.0000x reference)
//
#include <hip/hip_runtime.h>
#include <hip/hip_bf16.h>
#include <cstdint>

// B=2, S=2048, E=1024, H=16, HD=64
#define SS 2048
#define EE 1024
#define HH 16
#define HDD 64

typedef __attribute__((ext_vector_type(8))) __bf16 bf16x8;
typedef __attribute__((ext_vector_type(4))) float f32x4;

#define MFMA16(a, b, c) __builtin_amdgcn_mfma_f32_16x16x32_bf16((a), (b), (c), 0, 0, 0)

__device__ __forceinline__ unsigned short f2bf(float f) {
    unsigned int u = __builtin_bit_cast(unsigned int, f);
    u += 0x7FFFu + ((u >> 16) & 1u);   // round-to-nearest-even
    return (unsigned short)(u >> 16);
}

__device__ __forceinline__ float bcf(unsigned int u) {
    return __builtin_bit_cast(float, u);
}

// async global->LDS, 16B per lane; LDS dest is wave-uniform base + lane*16
__device__ __forceinline__ void gll16(const unsigned short* g, unsigned short* l) {
    __builtin_amdgcn_global_load_lds(
        (__attribute__((address_space(1))) unsigned int*)g,
        (__attribute__((address_space(3))) unsigned int*)l, 16, 0, 0);
}

// v_permlane32_swap_b32: a' = {A.low32, B.low32}, b' = {A.high32, B.high32}
__device__ __forceinline__ void pl32swap(unsigned int& a, unsigned int& b) {
#if __has_builtin(__builtin_amdgcn_permlane32_swap)
    auto r = __builtin_amdgcn_permlane32_swap(a, b, false, false);
    a = r[0]; b = r[1];
#else
    unsigned int as = __shfl_xor(a, 32, 64), bs = __shfl_xor(b, 32, 64);
    const bool hi = (threadIdx.x & 32) != 0;
    unsigned int na = hi ? bs : a, nb = hi ? b : as;
    a = na; b = nb;
#endif
}

// v_permlane16_swap_b32: a' = {A.r0, B.r0, A.r2, B.r2}, b' = {A.r1, B.r1, A.r3, B.r3}  (16-lane rows)
__device__ __forceinline__ void pl16swap(unsigned int& a, unsigned int& b) {
#if __has_builtin(__builtin_amdgcn_permlane16_swap)
    auto r = __builtin_amdgcn_permlane16_swap(a, b, false, false);
    a = r[0]; b = r[1];
#else
    unsigned int as = __shfl_xor(a, 16, 64), bs = __shfl_xor(b, 16, 64);
    const bool odd = (threadIdx.x & 16) != 0;
    unsigned int na = odd ? bs : a, nb = odd ? b : as;
    a = na; b = nb;
#endif
}

// ---------------- fp32 -> bf16 convert (x + 4 weights) ----------------
__global__ __launch_bounds__(256) void cvt_all(
    const float* __restrict__ x, const float* __restrict__ wq, const float* __restrict__ wk,
    const float* __restrict__ wv, const float* __restrict__ wo,
    unsigned short* __restrict__ xb, unsigned short* __restrict__ wqb, unsigned short* __restrict__ wkb,
    unsigned short* __restrict__ wvb, unsigned short* __restrict__ wob) {
    int idx = blockIdx.x * 256 + threadIdx.x;
    int i4 = idx << 2;                       // 4 floats per thread
    const float* src;
    unsigned short* dst;
    int off;
    if (i4 < 4194304) { src = x; dst = xb; off = i4; }
    else {
        int w = (i4 - 4194304) >> 20;        // 0..3
        off = (i4 - 4194304) & 1048575;
        if (w == 0) { src = wq; dst = wqb; }
        else if (w == 1) { src = wk; dst = wkb; }
        else if (w == 2) { src = wv; dst = wvb; }
        else { src = wo; dst = wob; }
    }
    float4 v = *(const float4*)&src[off];
    unsigned int p0 = (unsigned int)f2bf(v.x) | ((unsigned int)f2bf(v.y) << 16);
    unsigned int p1 = (unsigned int)f2bf(v.z) | ((unsigned int)f2bf(v.w) << 16);
    uint2 u; u.x = p0; u.y = p1;
    *(uint2*)&dst[off] = u;
}

// ---------------- BT GEMM, DOUBLE-BUFFERED (one barrier per K-iter) ----------------
// ROUND-9 CONFIG (best: qkv 128x128 grid 768, out 128x64 grid 512). LDS passed in
// (hoisted) so template instantiations share the allocation.
// MODE 0: bf16 out per-head [B,H,S,HD]  (Q)
// MODE 1: fp32 out [M,N]                (final projection)
// MODE 3: bf16 K in MFMA A-fragment order
// MODE 4: bf16 V in MFMA B-fragment order
template <int MODE, int BMT, int BNT>
__device__ __forceinline__ void gemm_core(
    unsigned short* __restrict__ lsA,        // [2][BMT*32]
    unsigned short* __restrict__ lsB,        // [2][BNT*32]
    const unsigned short* __restrict__ A, const unsigned short* __restrict__ W,
    const float* __restrict__ bias, void* __restrict__ out, int bm, int bn) {
    constexpr int IT = BMT / 32, JT = BNT / 32;
    constexpr int ASTR = BMT * 32, BSTR = BNT * 32;
    const int t = threadIdx.x;
    const int lane = t & 63, l15 = lane & 15, quad = lane >> 4;
    const int wave = t >> 6;
    const int wm = (wave >> 1) * (BMT / 2), wn = (wave & 1) * (BNT / 2);

    // staging: lane t -> physical chunk (t&3) of row (t>>2); load logical chunk (t&3)^((t>>3)&3)
    const int cg = ((t & 3) ^ ((t >> 3) & 3)) * 8;
    const unsigned short* ga = A + (size_t)(bm + (t >> 2)) * 1024 + cg;
    const unsigned short* gb = W + (size_t)(bn + (t >> 2)) * 1024 + cg;

    f32x4 acc[IT][JT];
    for (int i = 0; i < IT; i++)
        for (int j = 0; j < JT; j++) acc[i][j] = (f32x4){0.f, 0.f, 0.f, 0.f};

    const int swz = (l15 >> 1) & 3;  // (row>>1)&3 for row = wX + i*16 + l15

    // stage K-slab 0 into buffer 0
    gll16(ga, &lsA[t * 8]);
    if (BMT == 128) gll16(ga + 64 * 1024, &lsA[2048 + t * 8]);
    gll16(gb, &lsB[t * 8]);
    if (BNT == 128) gll16(gb + 64 * 1024, &lsB[2048 + t * 8]);

    for (int it = 0; it < 32; it++) {
        const int cur = it & 1, nxt = cur ^ 1;
        __syncthreads();  // cur staging done (issued a full body ago); prev reads of nxt drained

        if (it < 31) {
            const int k0 = (it + 1) * 32;
            gll16(ga + k0, &lsA[nxt * ASTR + t * 8]);
            if (BMT == 128) gll16(ga + k0 + 64 * 1024, &lsA[nxt * ASTR + 2048 + t * 8]);
            gll16(gb + k0, &lsB[nxt * BSTR + t * 8]);
            if (BNT == 128) gll16(gb + k0 + 64 * 1024, &lsB[nxt * BSTR + 2048 + t * 8]);
        }

        bf16x8 af[IT], bfr[JT];
        for (int i = 0; i < IT; i++)
            af[i] = *(const bf16x8*)&lsA[cur * ASTR + (wm + i * 16 + l15) * 32 + ((quad ^ swz) * 8)];
        for (int j = 0; j < JT; j++)
            bfr[j] = *(const bf16x8*)&lsB[cur * BSTR + (wn + j * 16 + l15) * 32 + ((quad ^ swz) * 8)];
        for (int i = 0; i < IT; i++)
            for (int j = 0; j < JT; j++) acc[i][j] = MFMA16(af[i], bfr[j], acc[i][j]);
    }

    // epilogue: C row = quad*4+reg, col = l15 per 16x16 tile (m89-verified)
    for (int j = 0; j < JT; j++) {
        int n = bn + wn + j * 16 + l15;
        float bj = bias[n];
        for (int i = 0; i < IT; i++) {
            int m0 = bm + wm + i * 16 + quad * 4;
            int srow0 = m0 & 2047, bidx = m0 >> 11;
            if (MODE == 3) {
                size_t headb = ((size_t)bidx * HH + (n >> 6)) * (SS * HDD);
                size_t base = headb + (size_t)(srow0 >> 6) * 4096 +
                              (size_t)(((srow0 >> 4) & 3) * 8 + ((n & 63) >> 3)) * 128 + (n & 7);
                for (int rg = 0; rg < 4; rg++)
                    ((unsigned short*)out)[base + (size_t)((srow0 & 15) + rg) * 8] = f2bf(acc[i][j][rg] + bj);
            } else if (MODE == 4) {
                size_t headb = ((size_t)bidx * HH + (n >> 6)) * (SS * HDD);
                size_t addr = headb + (size_t)(srow0 >> 6) * 4096 + (size_t)((n & 63) >> 4) * 1024 +
                              (size_t)(((srow0 >> 5) & 1) * 4 + ((srow0 >> 3) & 3)) * 128 +
                              (size_t)(n & 15) * 8 + (srow0 & 7);
                float v0 = acc[i][j][0] + bj, v1 = acc[i][j][1] + bj;
                float v2 = acc[i][j][2] + bj, v3 = acc[i][j][3] + bj;
                uint2 w;
                w.x = (unsigned int)f2bf(v0) | ((unsigned int)f2bf(v1) << 16);
                w.y = (unsigned int)f2bf(v2) | ((unsigned int)f2bf(v3) << 16);
                *(uint2*)&((unsigned short*)out)[addr] = w;
            } else {
                for (int rg = 0; rg < 4; rg++) {
                    float val = acc[i][j][rg] + bj;
                    int m = m0 + rg;
                    if (MODE == 0) {
                        ((unsigned short*)out)[(((size_t)(m >> 11) * HH + (n >> 6)) * SS + (m & 2047)) * HDD + (n & 63)] = f2bf(val);
                    } else {
                        ((float*)out)[(size_t)m * 1024 + n] = val;
                    }
                }
            }
        }
    }
}

// grid 768 1-D (round-9 config); XCD swizzle: same-by blocks share an XCD
__global__ __launch_bounds__(256) void gemm_qkv(
    const unsigned short* __restrict__ xb,
    const unsigned short* __restrict__ wqb, const unsigned short* __restrict__ wkb,
    const unsigned short* __restrict__ wvb,
    const float* __restrict__ bq, const float* __restrict__ bk, const float* __restrict__ bv,
    unsigned short* qb, unsigned short* kb, unsigned short* vtb) {
    __shared__ unsigned short shA[2 * 4096];   // shared across all 3 instantiations
    __shared__ unsigned short shB[2 * 4096];
    const int blk = blockIdx.x;
    const int u = blk & 7, r = blk >> 3;
    const int by = u + 8 * (r & 3);          // 0..31
    const int rest = r >> 2;                 // 0..23
    const int bx = rest & 7, z = rest >> 3;  // 0..7, 0..2
    if (z == 0)      gemm_core<0, 128, 128>(shA, shB, xb, wqb, bq, qb,  by * 128, bx * 128);
    else if (z == 1) gemm_core<3, 128, 128>(shA, shB, xb, wkb, bk, kb,  by * 128, bx * 128);
    else             gemm_core<4, 128, 128>(shA, shB, xb, wvb, bv, vtb, by * 128, bx * 128);
}

// grid 512 1-D (round-9 config: 128x64 tiles)
__global__ __launch_bounds__(256) void gemm_out(
    const unsigned short* __restrict__ ob, const unsigned short* __restrict__ wob,
    const float* __restrict__ bo, float* __restrict__ out) {
    __shared__ unsigned short shA[2 * 4096];
    __shared__ unsigned short shB[2 * 2048];
    const int blk = blockIdx.x;
    const int u = blk & 7, r = blk >> 3;
    const int by = u + 8 * (r & 3);          // 0..31
    const int bx = r >> 2;                   // 0..15
    gemm_core<1, 128, 64>(shA, shB, ob, wob, bo, out, by * 128, bx * 64);
}

// ---------------- flash attention: INTRA-BLOCK SPLIT-K, 8 waves ----------------
// ROUND-11: P never touches LDS. S^T = mfma(K,Q) is transposed to PV A-fragment
// order fully in-register via permlane32_swap + permlane16_swap (the transpose is
// l15-preserving: data only moves among lanes {l15, +16, +32, +48}).
// Mapping (verified): src word (quad 2a_s+b_s, j, h) -> dest quad 2(j&1)+a_s,
// ks=j>>1, slot p=2*b_s+h. permlane32_swap(W[2k],W[2k+1]) then permlane16_swap
// of its two results delivers slots (p0,p1)/(p2,p3) directly.
// Also: denominator via per-lane f32 sums of the TRUNCATED bf16 P summands
// (bit-extracted from packed words -> numerics match the old P.ones MFMA path;
// truncation bias cancels in the ratio), reduced once after the loop with a
// xor16/xor32 butterfly + 4 shuffles into C-layout (src lane = 20*quad+rg).
// LDS 69632 -> 40960 B (combine buffers now set the size) -> 3-4 blocks/CU;
// launch_bounds (512,6) caps VGPR at ~85 to realize 3 blocks/CU.
// MFMA/iter: 32 (16 QK^T + 16 PV); LDS traffic/wave/iter: 16 KB (was 24 KB).
__global__ __launch_bounds__(512, 6) void attn_fwd(
    const unsigned short* __restrict__ qb, const unsigned short* __restrict__ kb,
    const unsigned short* __restrict__ vtb, unsigned short* __restrict__ ob) {
    __shared__ unsigned short sh[20480];  // lsK[2][4096] | lsV[2][4096]; combine aliases all 40960 B
    unsigned short* lsK = sh;
    unsigned short* lsV = sh + 8192;
    const int t = threadIdx.x, lane = t & 63, l15 = lane & 15, quad = lane >> 4;
    const int wave = t >> 6;          // 0..7
    const int half = wave >> 2;       // key-half
    const int wq = wave & 3;          // q-wave within half
    const int tg = t & 255;           // thread index within half-group
    const int blk = blockIdx.x;
    const int u = blk & 7, r = blk >> 3;
    const int bh = u + 8 * (r & 3);   // 0..31: 4 heads per XCD
    const int qt = r >> 2;            // 0..15
    const size_t hoff = (size_t)bh * (SS * HDD);
    const float C = 0.125f * 1.44269504088896f;  // 1/sqrt(HD) * log2(e)

    // Q fragments in registers, pre-scaled by C (used as B-operand for S^T)
    bf16x8 qf[2][2];
    const int qrow = qt * 128 + wq * 32;
    for (int i = 0; i < 2; i++)
        for (int ks = 0; ks < 2; ks++) {
            bf16x8 raw = *(const bf16x8*)&qb[hoff + (size_t)(qrow + i * 16 + l15) * HDD + ks * 32 + quad * 8];
            unsigned short tmp[8];
            *(bf16x8*)tmp = raw;
            for (int j = 0; j < 8; j++) {
                float f = __builtin_bit_cast(float, (unsigned int)tmp[j] << 16);
                tmp[j] = f2bf(f * C);
            }
            qf[i][ks] = *(const bf16x8*)tmp;
        }

    f32x4 o[2][4];
    float ps[2] = {0.f, 0.f};         // per-lane denominator partials (rows i*16+l15, this quad's keys)
    for (int i = 0; i < 2; i++)
        for (int jh = 0; jh < 4; jh++) o[i][jh] = (f32x4){0.f, 0.f, 0.f, 0.f};

    // this half's 16 fragment-order tiles
    const unsigned short* gk = kb + hoff + (size_t)half * 16 * 4096;
    const unsigned short* gv = vtb + hoff + (size_t)half * 16 * 4096;
    unsigned short* myK = lsK + half * 4096;
    unsigned short* myV = lsV + half * 4096;
    const int foff = quad * 128 + l15 * 8;  // fragment offset within a tile

    // stage tile 0
    gll16(gk + tg * 8, myK + tg * 8);
    gll16(gk + 2048 + tg * 8, myK + 2048 + tg * 8);
    gll16(gv + tg * 8, myV + tg * 8);
    gll16(gv + 2048 + tg * 8, myV + 2048 + tg * 8);

    for (int kt = 0; kt < 16; kt++) {
        __syncthreads();  // staging drained (vmcnt(0) before s_barrier) & visible

        // K fragments from LDS (plain offsets, min-aliasing)
        bf16x8 kfr[4][2];
        for (int j = 0; j < 4; j++)
            for (int ks = 0; ks < 2; ks++)
                kfr[j][ks] = *(const bf16x8*)&myK[j * 1024 + ks * 512 + foff];

        // S^T = K (CQ)^T : tile(j,i) rows = keys j*16+quad*4+rg, col = qrow i*16+l15
        f32x4 st[2][4];
        for (int j = 0; j < 4; j++)
            for (int i = 0; i < 2; i++) {
                f32x4 z = (f32x4){0.f, 0.f, 0.f, 0.f};
                z = MFMA16(kfr[j][0], qf[i][0], z);
                z = MFMA16(kfr[j][1], qf[i][1], z);
                st[i][j] = z;
            }

        // P = exp2(S^T): pack to bf16 pairs, accumulate truncated row-sums,
        // transpose in-register to PV A-fragment order (no LDS).
        bf16x8 pf[2][2];
        for (int i = 0; i < 2; i++) {
            unsigned int W[4][2];
            float accp = 0.f;
            for (int j = 0; j < 4; j++) {
                float e0 = __builtin_amdgcn_exp2f(st[i][j][0]);
                float e1 = __builtin_amdgcn_exp2f(st[i][j][1]);
                float e2 = __builtin_amdgcn_exp2f(st[i][j][2]);
                float e3 = __builtin_amdgcn_exp2f(st[i][j][3]);
                unsigned int w0 = (__builtin_bit_cast(unsigned int, e0) >> 16) |
                                  (__builtin_bit_cast(unsigned int, e1) & 0xFFFF0000u);
                unsigned int w1 = (__builtin_bit_cast(unsigned int, e2) >> 16) |
                                  (__builtin_bit_cast(unsigned int, e3) & 0xFFFF0000u);
                W[j][0] = w0; W[j][1] = w1;
                // truncated-bf16 summands (match old MFMA P.ones numerics)
                accp += (bcf(w0 << 16) + bcf(w0 & 0xFFFF0000u)) +
                        (bcf(w1 << 16) + bcf(w1 & 0xFFFF0000u));
            }
            ps[i] += accp;

            unsigned int P0[4], P1[4];
            for (int h = 0; h < 2; h++) {
                unsigned int x = W[0][h], y = W[1][h];
                pl32swap(x, y);           // x:(j=a, from half0)  y:(j=a, from half1)
                pl16swap(x, y);           // x:(b_s=0)  y:(b_s=1), each with a_s==own b
                P0[h] = x; P0[2 + h] = y;
                unsigned int x2 = W[2][h], y2 = W[3][h];
                pl32swap(x2, y2);
                pl16swap(x2, y2);
                P1[h] = x2; P1[2 + h] = y2;
            }
            union { unsigned int u4[4]; bf16x8 v; } cv0, cv1;
            for (int p = 0; p < 4; p++) { cv0.u4[p] = P0[p]; cv1.u4[p] = P1[p]; }
            pf[i][0] = cv0.v;
            pf[i][1] = cv1.v;
        }

        // O += P V   (V fragments streamed from LDS)
        for (int jh = 0; jh < 4; jh++) {
            bf16x8 v0 = *(const bf16x8*)&myV[jh * 1024 + foff];
            bf16x8 v1 = *(const bf16x8*)&myV[jh * 1024 + 512 + foff];
            for (int i = 0; i < 2; i++) {
                o[i][jh] = MFMA16(pf[i][0], v0, o[i][jh]);
                o[i][jh] = MFMA16(pf[i][1], v1, o[i][jh]);
            }
        }

        if (kt < 15) {
            __syncthreads();  // all reads of current tile done before restage
            const unsigned short* gkn = gk + (kt + 1) * 4096;
            const unsigned short* gvn = gv + (kt + 1) * 4096;
            gll16(gkn + tg * 8, myK + tg * 8);
            gll16(gkn + 2048 + tg * 8, myK + 2048 + tg * 8);
            gll16(gvn + tg * 8, myV + tg * 8);
            gll16(gvn + 2048 + tg * 8, myV + 2048 + tg * 8);
        }
    }

    // ----- denominator: butterfly over quads, then redistribute to C-layout -----
    // After xor16+xor32, every lane holds this half's full row-sum for row i*16+l15.
    // Epilogue needs row quad*4+rg at slot [i][rg]: pull from lane 16*quad + (4*quad+rg).
    float mysum[2][4];
    for (int i = 0; i < 2; i++) {
        float xv = ps[i];
        xv += __shfl_xor(xv, 16, 64);
        xv += __shfl_xor(xv, 32, 64);
        for (int rg = 0; rg < 4; rg++)
            mysum[i][rg] = __shfl(xv, quad * 20 + rg, 64);
    }

    // ----- combine halves via LDS (fp32), then epilogue -----
    __syncthreads();  // all LDS reads done before alias overwrite
    float* cb = (float*)sh;           // N: [32 elems][4 wq][64 lanes], element-major (conflict-free)
    float* lb = cb + 8192;            // l: [8 elems][4 wq][64 lanes]
    const int lslot = wq * 64 + lane;
    if (half == 1) {
        for (int i = 0; i < 2; i++)
            for (int jh = 0; jh < 4; jh++)
                for (int rg = 0; rg < 4; rg++)
                    cb[(i * 16 + jh * 4 + rg) * 256 + lslot] = o[i][jh][rg];
        for (int i = 0; i < 2; i++)
            for (int rg = 0; rg < 4; rg++)
                lb[(i * 4 + rg) * 256 + lslot] = mysum[i][rg];
    }
    __syncthreads();
    if (half == 0) {
        const int b = bh >> 4, h = bh & 15;
        for (int i = 0; i < 2; i++)
            for (int rg = 0; rg < 4; rg++) {
                float inv = 1.f / (mysum[i][rg] + lb[(i * 4 + rg) * 256 + lslot]);
                int srow = qrow + i * 16 + quad * 4 + rg;
                size_t rowoff = ((size_t)b * SS + srow) * EE + h * 64;
                for (int jh = 0; jh < 4; jh++) {
                    float val = o[i][jh][rg] + cb[(i * 16 + jh * 4 + rg) * 256 + lslot];
                    ob[rowoff + jh * 16 + l15] = f2bf(val * inv);
                }
            }
    }
}

extern "C" void kernel_launch(void* const* d_in, const int* in_sizes, int n_in,
                              void* d_out, int out_size, void* d_ws, size_t ws_size,
                              hipStream_t stream) {
    const float* x  = (const float*)d_in[0];
    const float* wq = (const float*)d_in[1];
    const float* bq = (const float*)d_in[2];
    const float* wk = (const float*)d_in[3];
    const float* bk = (const float*)d_in[4];
    const float* wv = (const float*)d_in[5];
    const float* bv = (const float*)d_in[6];
    const float* wo = (const float*)d_in[7];
    const float* bo = (const float*)d_in[8];

    char* ws = (char*)d_ws;
    unsigned short* xb  = (unsigned short*)(ws + 0);          // 8 MB, reused as ob after qkv
    unsigned short* wqb = (unsigned short*)(ws + 8388608);    // 2 MB
    unsigned short* wkb = (unsigned short*)(ws + 10485760);
    unsigned short* wvb = (unsigned short*)(ws + 12582912);
    unsigned short* wob = (unsigned short*)(ws + 14680064);
    unsigned short* qb  = (unsigned short*)(ws + 16777216);   // 8 MB each
    unsigned short* kb  = (unsigned short*)(ws + 25165824);   // K in fragment order
    unsigned short* vtb = (unsigned short*)(ws + 33554432);   // V in fragment order
    unsigned short* ob  = xb;  // x no longer needed after qkv GEMM

    cvt_all<<<8192, 256, 0, stream>>>(x, wq, wk, wv, wo, xb, wqb, wkb, wvb, wob);
    gemm_qkv<<<768, 256, 0, stream>>>(xb, wqb, wkb, wvb, bq, bk, bv, qb, kb, vtb);
    attn_fwd<<<512, 512, 0, stream>>>(qb, kb, vtb, ob);
    gemm_out<<<512, 256, 0, stream>>>(ob, wob, bo, (float*)d_out);
}

// Round 2
// 189.582 us; speedup vs baseline: 1.3408x; 1.3408x over previous
//
#include <hip/hip_runtime.h>
#include <hip/hip_bf16.h>
#include <cstdint>

// B=2, S=2048, E=1024, H=16, HD=64
#define SS 2048
#define EE 1024
#define HH 16
#define HDD 64

typedef __attribute__((ext_vector_type(8))) __bf16 bf16x8;
typedef __attribute__((ext_vector_type(4))) float f32x4;

#define MFMA16(a, b, c) __builtin_amdgcn_mfma_f32_16x16x32_bf16((a), (b), (c), 0, 0, 0)

__device__ __forceinline__ unsigned short f2bf(float f) {
    unsigned int u = __builtin_bit_cast(unsigned int, f);
    u += 0x7FFFu + ((u >> 16) & 1u);   // round-to-nearest-even
    return (unsigned short)(u >> 16);
}

__device__ __forceinline__ float bcf(unsigned int u) {
    return __builtin_bit_cast(float, u);
}

// async global->LDS, 16B per lane; LDS dest is wave-uniform base + lane*16
__device__ __forceinline__ void gll16(const unsigned short* g, unsigned short* l) {
    __builtin_amdgcn_global_load_lds(
        (__attribute__((address_space(1))) unsigned int*)g,
        (__attribute__((address_space(3))) unsigned int*)l, 16, 0, 0);
}

// v_permlane32_swap_b32: a' = {A.low32, B.low32}, b' = {A.high32, B.high32}
__device__ __forceinline__ void pl32swap(unsigned int& a, unsigned int& b) {
#if __has_builtin(__builtin_amdgcn_permlane32_swap)
    auto r = __builtin_amdgcn_permlane32_swap(a, b, false, false);
    a = r[0]; b = r[1];
#else
    unsigned int as = __shfl_xor(a, 32, 64), bs = __shfl_xor(b, 32, 64);
    const bool hi = (threadIdx.x & 32) != 0;
    unsigned int na = hi ? bs : a, nb = hi ? b : as;
    a = na; b = nb;
#endif
}

// v_permlane16_swap_b32: a' = {A.r0, B.r0, A.r2, B.r2}, b' = {A.r1, B.r1, A.r3, B.r3}  (16-lane rows)
__device__ __forceinline__ void pl16swap(unsigned int& a, unsigned int& b) {
#if __has_builtin(__builtin_amdgcn_permlane16_swap)
    auto r = __builtin_amdgcn_permlane16_swap(a, b, false, false);
    a = r[0]; b = r[1];
#else
    unsigned int as = __shfl_xor(a, 16, 64), bs = __shfl_xor(b, 16, 64);
    const bool odd = (threadIdx.x & 16) != 0;
    unsigned int na = odd ? bs : a, nb = odd ? b : as;
    a = na; b = nb;
#endif
}

// ---------------- fp32 -> bf16 convert (x + 4 weights) ----------------
__global__ __launch_bounds__(256) void cvt_all(
    const float* __restrict__ x, const float* __restrict__ wq, const float* __restrict__ wk,
    const float* __restrict__ wv, const float* __restrict__ wo,
    unsigned short* __restrict__ xb, unsigned short* __restrict__ wqb, unsigned short* __restrict__ wkb,
    unsigned short* __restrict__ wvb, unsigned short* __restrict__ wob) {
    int idx = blockIdx.x * 256 + threadIdx.x;
    int i4 = idx << 2;                       // 4 floats per thread
    const float* src;
    unsigned short* dst;
    int off;
    if (i4 < 4194304) { src = x; dst = xb; off = i4; }
    else {
        int w = (i4 - 4194304) >> 20;        // 0..3
        off = (i4 - 4194304) & 1048575;
        if (w == 0) { src = wq; dst = wqb; }
        else if (w == 1) { src = wk; dst = wkb; }
        else if (w == 2) { src = wv; dst = wvb; }
        else { src = wo; dst = wob; }
    }
    float4 v = *(const float4*)&src[off];
    unsigned int p0 = (unsigned int)f2bf(v.x) | ((unsigned int)f2bf(v.y) << 16);
    unsigned int p1 = (unsigned int)f2bf(v.z) | ((unsigned int)f2bf(v.w) << 16);
    uint2 u; u.x = p0; u.y = p1;
    *(uint2*)&dst[off] = u;
}

// ---------------- BT GEMM, DOUBLE-BUFFERED (one barrier per K-iter) ----------------
// ROUND-9 CONFIG (best: qkv 128x128 grid 768, out 128x64 grid 512). LDS passed in
// (hoisted) so template instantiations share the allocation.
// MODE 0: bf16 out per-head [B,H,S,HD]  (Q)
// MODE 1: fp32 out [M,N]                (final projection)
// MODE 3: bf16 K in MFMA A-fragment order
// MODE 4: bf16 V in MFMA B-fragment order
template <int MODE, int BMT, int BNT>
__device__ __forceinline__ void gemm_core(
    unsigned short* __restrict__ lsA,        // [2][BMT*32]
    unsigned short* __restrict__ lsB,        // [2][BNT*32]
    const unsigned short* __restrict__ A, const unsigned short* __restrict__ W,
    const float* __restrict__ bias, void* __restrict__ out, int bm, int bn) {
    constexpr int IT = BMT / 32, JT = BNT / 32;
    constexpr int ASTR = BMT * 32, BSTR = BNT * 32;
    const int t = threadIdx.x;
    const int lane = t & 63, l15 = lane & 15, quad = lane >> 4;
    const int wave = t >> 6;
    const int wm = (wave >> 1) * (BMT / 2), wn = (wave & 1) * (BNT / 2);

    // staging: lane t -> physical chunk (t&3) of row (t>>2); load logical chunk (t&3)^((t>>3)&3)
    const int cg = ((t & 3) ^ ((t >> 3) & 3)) * 8;
    const unsigned short* ga = A + (size_t)(bm + (t >> 2)) * 1024 + cg;
    const unsigned short* gb = W + (size_t)(bn + (t >> 2)) * 1024 + cg;

    f32x4 acc[IT][JT];
    for (int i = 0; i < IT; i++)
        for (int j = 0; j < JT; j++) acc[i][j] = (f32x4){0.f, 0.f, 0.f, 0.f};

    const int swz = (l15 >> 1) & 3;  // (row>>1)&3 for row = wX + i*16 + l15

    // stage K-slab 0 into buffer 0
    gll16(ga, &lsA[t * 8]);
    if (BMT == 128) gll16(ga + 64 * 1024, &lsA[2048 + t * 8]);
    gll16(gb, &lsB[t * 8]);
    if (BNT == 128) gll16(gb + 64 * 1024, &lsB[2048 + t * 8]);

    for (int it = 0; it < 32; it++) {
        const int cur = it & 1, nxt = cur ^ 1;
        __syncthreads();  // cur staging done (issued a full body ago); prev reads of nxt drained

        if (it < 31) {
            const int k0 = (it + 1) * 32;
            gll16(ga + k0, &lsA[nxt * ASTR + t * 8]);
            if (BMT == 128) gll16(ga + k0 + 64 * 1024, &lsA[nxt * ASTR + 2048 + t * 8]);
            gll16(gb + k0, &lsB[nxt * BSTR + t * 8]);
            if (BNT == 128) gll16(gb + k0 + 64 * 1024, &lsB[nxt * BSTR + 2048 + t * 8]);
        }

        bf16x8 af[IT], bfr[JT];
        for (int i = 0; i < IT; i++)
            af[i] = *(const bf16x8*)&lsA[cur * ASTR + (wm + i * 16 + l15) * 32 + ((quad ^ swz) * 8)];
        for (int j = 0; j < JT; j++)
            bfr[j] = *(const bf16x8*)&lsB[cur * BSTR + (wn + j * 16 + l15) * 32 + ((quad ^ swz) * 8)];
        for (int i = 0; i < IT; i++)
            for (int j = 0; j < JT; j++) acc[i][j] = MFMA16(af[i], bfr[j], acc[i][j]);
    }

    // epilogue: C row = quad*4+reg, col = l15 per 16x16 tile (m89-verified)
    for (int j = 0; j < JT; j++) {
        int n = bn + wn + j * 16 + l15;
        float bj = bias[n];
        for (int i = 0; i < IT; i++) {
            int m0 = bm + wm + i * 16 + quad * 4;
            int srow0 = m0 & 2047, bidx = m0 >> 11;
            if (MODE == 3) {
                size_t headb = ((size_t)bidx * HH + (n >> 6)) * (SS * HDD);
                size_t base = headb + (size_t)(srow0 >> 6) * 4096 +
                              (size_t)(((srow0 >> 4) & 3) * 8 + ((n & 63) >> 3)) * 128 + (n & 7);
                for (int rg = 0; rg < 4; rg++)
                    ((unsigned short*)out)[base + (size_t)((srow0 & 15) + rg) * 8] = f2bf(acc[i][j][rg] + bj);
            } else if (MODE == 4) {
                size_t headb = ((size_t)bidx * HH + (n >> 6)) * (SS * HDD);
                size_t addr = headb + (size_t)(srow0 >> 6) * 4096 + (size_t)((n & 63) >> 4) * 1024 +
                              (size_t)(((srow0 >> 5) & 1) * 4 + ((srow0 >> 3) & 3)) * 128 +
                              (size_t)(n & 15) * 8 + (srow0 & 7);
                float v0 = acc[i][j][0] + bj, v1 = acc[i][j][1] + bj;
                float v2 = acc[i][j][2] + bj, v3 = acc[i][j][3] + bj;
                uint2 w;
                w.x = (unsigned int)f2bf(v0) | ((unsigned int)f2bf(v1) << 16);
                w.y = (unsigned int)f2bf(v2) | ((unsigned int)f2bf(v3) << 16);
                *(uint2*)&((unsigned short*)out)[addr] = w;
            } else {
                for (int rg = 0; rg < 4; rg++) {
                    float val = acc[i][j][rg] + bj;
                    int m = m0 + rg;
                    if (MODE == 0) {
                        ((unsigned short*)out)[(((size_t)(m >> 11) * HH + (n >> 6)) * SS + (m & 2047)) * HDD + (n & 63)] = f2bf(val);
                    } else {
                        ((float*)out)[(size_t)m * 1024 + n] = val;
                    }
                }
            }
        }
    }
}

// grid 768 1-D (round-9 config); XCD swizzle: same-by blocks share an XCD
__global__ __launch_bounds__(256) void gemm_qkv(
    const unsigned short* __restrict__ xb,
    const unsigned short* __restrict__ wqb, const unsigned short* __restrict__ wkb,
    const unsigned short* __restrict__ wvb,
    const float* __restrict__ bq, const float* __restrict__ bk, const float* __restrict__ bv,
    unsigned short* qb, unsigned short* kb, unsigned short* vtb) {
    __shared__ unsigned short shA[2 * 4096];   // shared across all 3 instantiations
    __shared__ unsigned short shB[2 * 4096];
    const int blk = blockIdx.x;
    const int u = blk & 7, r = blk >> 3;
    const int by = u + 8 * (r & 3);          // 0..31
    const int rest = r >> 2;                 // 0..23
    const int bx = rest & 7, z = rest >> 3;  // 0..7, 0..2
    if (z == 0)      gemm_core<0, 128, 128>(shA, shB, xb, wqb, bq, qb,  by * 128, bx * 128);
    else if (z == 1) gemm_core<3, 128, 128>(shA, shB, xb, wkb, bk, kb,  by * 128, bx * 128);
    else             gemm_core<4, 128, 128>(shA, shB, xb, wvb, bv, vtb, by * 128, bx * 128);
}

// grid 512 1-D (round-9 config: 128x64 tiles)
__global__ __launch_bounds__(256) void gemm_out(
    const unsigned short* __restrict__ ob, const unsigned short* __restrict__ wob,
    const float* __restrict__ bo, float* __restrict__ out) {
    __shared__ unsigned short shA[2 * 4096];
    __shared__ unsigned short shB[2 * 2048];
    const int blk = blockIdx.x;
    const int u = blk & 7, r = blk >> 3;
    const int by = u + 8 * (r & 3);          // 0..31
    const int bx = r >> 2;                   // 0..15
    gemm_core<1, 128, 64>(shA, shB, ob, wob, bo, out, by * 128, bx * 64);
}

// ---------------- flash attention: INTRA-BLOCK SPLIT-K, 8 waves ----------------
// ROUND-12: round-11's in-register P transpose (permlane32/16_swap, P never
// touches LDS, bank conflicts 3.15M -> 0, LDS 69632 -> 40960) KEPT, but
// launch_bounds reverted (512,6) -> (512,4). The 6-wave cap squeezed VGPR to
// ~85 < live state (~100+) -> massive scratch spill (FETCH 100MB, WRITE 219MB,
// 113us). Occupancy is quantized by 8-wave blocks: 3 blocks/CU needs VGPR<=85
// (spills), 2 blocks/CU needs <=128 (fits). Take 2 blocks/CU, no spill.
// MFMA/iter: 32 (16 QK^T + 16 PV, P.ones MFMAs replaced by per-lane f32 sums);
// LDS traffic/wave/iter: 16 KB (was 24 KB).
__global__ __launch_bounds__(512, 4) void attn_fwd(
    const unsigned short* __restrict__ qb, const unsigned short* __restrict__ kb,
    const unsigned short* __restrict__ vtb, unsigned short* __restrict__ ob) {
    __shared__ unsigned short sh[20480];  // lsK[2][4096] | lsV[2][4096]; combine aliases all 40960 B
    unsigned short* lsK = sh;
    unsigned short* lsV = sh + 8192;
    const int t = threadIdx.x, lane = t & 63, l15 = lane & 15, quad = lane >> 4;
    const int wave = t >> 6;          // 0..7
    const int half = wave >> 2;       // key-half
    const int wq = wave & 3;          // q-wave within half
    const int tg = t & 255;           // thread index within half-group
    const int blk = blockIdx.x;
    const int u = blk & 7, r = blk >> 3;
    const int bh = u + 8 * (r & 3);   // 0..31: 4 heads per XCD
    const int qt = r >> 2;            // 0..15
    const size_t hoff = (size_t)bh * (SS * HDD);
    const float C = 0.125f * 1.44269504088896f;  // 1/sqrt(HD) * log2(e)

    // Q fragments in registers, pre-scaled by C (used as B-operand for S^T)
    bf16x8 qf[2][2];
    const int qrow = qt * 128 + wq * 32;
    for (int i = 0; i < 2; i++)
        for (int ks = 0; ks < 2; ks++) {
            bf16x8 raw = *(const bf16x8*)&qb[hoff + (size_t)(qrow + i * 16 + l15) * HDD + ks * 32 + quad * 8];
            unsigned short tmp[8];
            *(bf16x8*)tmp = raw;
            for (int j = 0; j < 8; j++) {
                float f = __builtin_bit_cast(float, (unsigned int)tmp[j] << 16);
                tmp[j] = f2bf(f * C);
            }
            qf[i][ks] = *(const bf16x8*)tmp;
        }

    f32x4 o[2][4];
    float ps[2] = {0.f, 0.f};         // per-lane denominator partials (rows i*16+l15, this quad's keys)
    for (int i = 0; i < 2; i++)
        for (int jh = 0; jh < 4; jh++) o[i][jh] = (f32x4){0.f, 0.f, 0.f, 0.f};

    // this half's 16 fragment-order tiles
    const unsigned short* gk = kb + hoff + (size_t)half * 16 * 4096;
    const unsigned short* gv = vtb + hoff + (size_t)half * 16 * 4096;
    unsigned short* myK = lsK + half * 4096;
    unsigned short* myV = lsV + half * 4096;
    const int foff = quad * 128 + l15 * 8;  // fragment offset within a tile

    // stage tile 0
    gll16(gk + tg * 8, myK + tg * 8);
    gll16(gk + 2048 + tg * 8, myK + 2048 + tg * 8);
    gll16(gv + tg * 8, myV + tg * 8);
    gll16(gv + 2048 + tg * 8, myV + 2048 + tg * 8);

    for (int kt = 0; kt < 16; kt++) {
        __syncthreads();  // staging drained (vmcnt(0) before s_barrier) & visible

        // K fragments from LDS (plain offsets, min-aliasing)
        bf16x8 kfr[4][2];
        for (int j = 0; j < 4; j++)
            for (int ks = 0; ks < 2; ks++)
                kfr[j][ks] = *(const bf16x8*)&myK[j * 1024 + ks * 512 + foff];

        // S^T = K (CQ)^T : tile(j,i) rows = keys j*16+quad*4+rg, col = qrow i*16+l15
        f32x4 st[2][4];
        for (int j = 0; j < 4; j++)
            for (int i = 0; i < 2; i++) {
                f32x4 z = (f32x4){0.f, 0.f, 0.f, 0.f};
                z = MFMA16(kfr[j][0], qf[i][0], z);
                z = MFMA16(kfr[j][1], qf[i][1], z);
                st[i][j] = z;
            }

        // P = exp2(S^T): pack to bf16 pairs, accumulate truncated row-sums,
        // transpose in-register to PV A-fragment order (no LDS).
        bf16x8 pf[2][2];
        for (int i = 0; i < 2; i++) {
            unsigned int W[4][2];
            float accp = 0.f;
            for (int j = 0; j < 4; j++) {
                float e0 = __builtin_amdgcn_exp2f(st[i][j][0]);
                float e1 = __builtin_amdgcn_exp2f(st[i][j][1]);
                float e2 = __builtin_amdgcn_exp2f(st[i][j][2]);
                float e3 = __builtin_amdgcn_exp2f(st[i][j][3]);
                unsigned int w0 = (__builtin_bit_cast(unsigned int, e0) >> 16) |
                                  (__builtin_bit_cast(unsigned int, e1) & 0xFFFF0000u);
                unsigned int w1 = (__builtin_bit_cast(unsigned int, e2) >> 16) |
                                  (__builtin_bit_cast(unsigned int, e3) & 0xFFFF0000u);
                W[j][0] = w0; W[j][1] = w1;
                // truncated-bf16 summands (match old MFMA P.ones numerics)
                accp += (bcf(w0 << 16) + bcf(w0 & 0xFFFF0000u)) +
                        (bcf(w1 << 16) + bcf(w1 & 0xFFFF0000u));
            }
            ps[i] += accp;

            unsigned int P0[4], P1[4];
            for (int h = 0; h < 2; h++) {
                unsigned int x = W[0][h], y = W[1][h];
                pl32swap(x, y);           // x:(j=a, from half0)  y:(j=a, from half1)
                pl16swap(x, y);           // x:(b_s=0)  y:(b_s=1), each with a_s==own b
                P0[h] = x; P0[2 + h] = y;
                unsigned int x2 = W[2][h], y2 = W[3][h];
                pl32swap(x2, y2);
                pl16swap(x2, y2);
                P1[h] = x2; P1[2 + h] = y2;
            }
            union { unsigned int u4[4]; bf16x8 v; } cv0, cv1;
            for (int p = 0; p < 4; p++) { cv0.u4[p] = P0[p]; cv1.u4[p] = P1[p]; }
            pf[i][0] = cv0.v;
            pf[i][1] = cv1.v;
        }

        // O += P V   (V fragments streamed from LDS)
        for (int jh = 0; jh < 4; jh++) {
            bf16x8 v0 = *(const bf16x8*)&myV[jh * 1024 + foff];
            bf16x8 v1 = *(const bf16x8*)&myV[jh * 1024 + 512 + foff];
            for (int i = 0; i < 2; i++) {
                o[i][jh] = MFMA16(pf[i][0], v0, o[i][jh]);
                o[i][jh] = MFMA16(pf[i][1], v1, o[i][jh]);
            }
        }

        if (kt < 15) {
            __syncthreads();  // all reads of current tile done before restage
            const unsigned short* gkn = gk + (kt + 1) * 4096;
            const unsigned short* gvn = gv + (kt + 1) * 4096;
            gll16(gkn + tg * 8, myK + tg * 8);
            gll16(gkn + 2048 + tg * 8, myK + 2048 + tg * 8);
            gll16(gvn + tg * 8, myV + tg * 8);
            gll16(gvn + 2048 + tg * 8, myV + 2048 + tg * 8);
        }
    }

    // ----- denominator: butterfly over quads, then redistribute to C-layout -----
    // After xor16+xor32, every lane holds this half's full row-sum for row i*16+l15.
    // Epilogue needs row quad*4+rg at slot [i][rg]: pull from lane 16*quad + (4*quad+rg).
    float mysum[2][4];
    for (int i = 0; i < 2; i++) {
        float xv = ps[i];
        xv += __shfl_xor(xv, 16, 64);
        xv += __shfl_xor(xv, 32, 64);
        for (int rg = 0; rg < 4; rg++)
            mysum[i][rg] = __shfl(xv, quad * 20 + rg, 64);
    }

    // ----- combine halves via LDS (fp32), then epilogue -----
    __syncthreads();  // all LDS reads done before alias overwrite
    float* cb = (float*)sh;           // N: [32 elems][4 wq][64 lanes], element-major (conflict-free)
    float* lb = cb + 8192;            // l: [8 elems][4 wq][64 lanes]
    const int lslot = wq * 64 + lane;
    if (half == 1) {
        for (int i = 0; i < 2; i++)
            for (int jh = 0; jh < 4; jh++)
                for (int rg = 0; rg < 4; rg++)
                    cb[(i * 16 + jh * 4 + rg) * 256 + lslot] = o[i][jh][rg];
        for (int i = 0; i < 2; i++)
            for (int rg = 0; rg < 4; rg++)
                lb[(i * 4 + rg) * 256 + lslot] = mysum[i][rg];
    }
    __syncthreads();
    if (half == 0) {
        const int b = bh >> 4, h = bh & 15;
        for (int i = 0; i < 2; i++)
            for (int rg = 0; rg < 4; rg++) {
                float inv = 1.f / (mysum[i][rg] + lb[(i * 4 + rg) * 256 + lslot]);
                int srow = qrow + i * 16 + quad * 4 + rg;
                size_t rowoff = ((size_t)b * SS + srow) * EE + h * 64;
                for (int jh = 0; jh < 4; jh++) {
                    float val = o[i][jh][rg] + cb[(i * 16 + jh * 4 + rg) * 256 + lslot];
                    ob[rowoff + jh * 16 + l15] = f2bf(val * inv);
                }
            }
    }
}

extern "C" void kernel_launch(void* const* d_in, const int* in_sizes, int n_in,
                              void* d_out, int out_size, void* d_ws, size_t ws_size,
                              hipStream_t stream) {
    const float* x  = (const float*)d_in[0];
    const float* wq = (const float*)d_in[1];
    const float* bq = (const float*)d_in[2];
    const float* wk = (const float*)d_in[3];
    const float* bk = (const float*)d_in[4];
    const float* wv = (const float*)d_in[5];
    const float* bv = (const float*)d_in[6];
    const float* wo = (const float*)d_in[7];
    const float* bo = (const float*)d_in[8];

    char* ws = (char*)d_ws;
    unsigned short* xb  = (unsigned short*)(ws + 0);          // 8 MB, reused as ob after qkv
    unsigned short* wqb = (unsigned short*)(ws + 8388608);    // 2 MB
    unsigned short* wkb = (unsigned short*)(ws + 10485760);
    unsigned short* wvb = (unsigned short*)(ws + 12582912);
    unsigned short* wob = (unsigned short*)(ws + 14680064);
    unsigned short* qb  = (unsigned short*)(ws + 16777216);   // 8 MB each
    unsigned short* kb  = (unsigned short*)(ws + 25165824);   // K in fragment order
    unsigned short* vtb = (unsigned short*)(ws + 33554432);   // V in fragment order
    unsigned short* ob  = xb;  // x no longer needed after qkv GEMM

    cvt_all<<<8192, 256, 0, stream>>>(x, wq, wk, wv, wo, xb, wqb, wkb, wvb, wob);
    gemm_qkv<<<768, 256, 0, stream>>>(xb, wqb, wkb, wvb, bq, bk, bv, qb, kb, vtb);
    attn_fwd<<<512, 512, 0, stream>>>(qb, kb, vtb, ob);
    gemm_out<<<512, 256, 0, stream>>>(ob, wob, bo, (float*)d_out);
}

// Round 3
// 187.807 us; speedup vs baseline: 1.3535x; 1.0095x over previous
//
#include <hip/hip_runtime.h>
#include <hip/hip_bf16.h>
#include <cstdint>

// B=2, S=2048, E=1024, H=16, HD=64
#define SS 2048
#define EE 1024
#define HH 16
#define HDD 64

typedef __attribute__((ext_vector_type(8))) __bf16 bf16x8;
typedef __attribute__((ext_vector_type(4))) float f32x4;

#define MFMA16(a, b, c) __builtin_amdgcn_mfma_f32_16x16x32_bf16((a), (b), (c), 0, 0, 0)

__device__ __forceinline__ unsigned short f2bf(float f) {
    unsigned int u = __builtin_bit_cast(unsigned int, f);
    u += 0x7FFFu + ((u >> 16) & 1u);   // round-to-nearest-even
    return (unsigned short)(u >> 16);
}

// async global->LDS, 16B per lane; LDS dest is wave-uniform base + lane*16
__device__ __forceinline__ void gll16(const unsigned short* g, unsigned short* l) {
    __builtin_amdgcn_global_load_lds(
        (__attribute__((address_space(1))) unsigned int*)g,
        (__attribute__((address_space(3))) unsigned int*)l, 16, 0, 0);
}

// v_permlane32_swap_b32: a' = {A.low32, B.low32}, b' = {A.high32, B.high32}
__device__ __forceinline__ void pl32swap(unsigned int& a, unsigned int& b) {
#if __has_builtin(__builtin_amdgcn_permlane32_swap)
    auto r = __builtin_amdgcn_permlane32_swap(a, b, false, false);
    a = r[0]; b = r[1];
#else
    unsigned int as = __shfl_xor(a, 32, 64), bs = __shfl_xor(b, 32, 64);
    const bool hi = (threadIdx.x & 32) != 0;
    unsigned int na = hi ? bs : a, nb = hi ? b : as;
    a = na; b = nb;
#endif
}

// v_permlane16_swap_b32: a' = {A.r0, B.r0, A.r2, B.r2}, b' = {A.r1, B.r1, A.r3, B.r3}  (16-lane rows)
__device__ __forceinline__ void pl16swap(unsigned int& a, unsigned int& b) {
#if __has_builtin(__builtin_amdgcn_permlane16_swap)
    auto r = __builtin_amdgcn_permlane16_swap(a, b, false, false);
    a = r[0]; b = r[1];
#else
    unsigned int as = __shfl_xor(a, 16, 64), bs = __shfl_xor(b, 16, 64);
    const bool odd = (threadIdx.x & 16) != 0;
    unsigned int na = odd ? bs : a, nb = odd ? b : as;
    a = na; b = nb;
#endif
}

// ---------------- fp32 -> bf16 convert (x + 4 weights) ----------------
__global__ __launch_bounds__(256) void cvt_all(
    const float* __restrict__ x, const float* __restrict__ wq, const float* __restrict__ wk,
    const float* __restrict__ wv, const float* __restrict__ wo,
    unsigned short* __restrict__ xb, unsigned short* __restrict__ wqb, unsigned short* __restrict__ wkb,
    unsigned short* __restrict__ wvb, unsigned short* __restrict__ wob) {
    int idx = blockIdx.x * 256 + threadIdx.x;
    int i4 = idx << 2;                       // 4 floats per thread
    const float* src;
    unsigned short* dst;
    int off;
    if (i4 < 4194304) { src = x; dst = xb; off = i4; }
    else {
        int w = (i4 - 4194304) >> 20;        // 0..3
        off = (i4 - 4194304) & 1048575;
        if (w == 0) { src = wq; dst = wqb; }
        else if (w == 1) { src = wk; dst = wkb; }
        else if (w == 2) { src = wv; dst = wvb; }
        else { src = wo; dst = wob; }
    }
    float4 v = *(const float4*)&src[off];
    unsigned int p0 = (unsigned int)f2bf(v.x) | ((unsigned int)f2bf(v.y) << 16);
    unsigned int p1 = (unsigned int)f2bf(v.z) | ((unsigned int)f2bf(v.w) << 16);
    uint2 u; u.x = p0; u.y = p1;
    *(uint2*)&dst[off] = u;
}

// ---------------- BT GEMM, DOUBLE-BUFFERED (one barrier per K-iter) ----------------
// ROUND-9 CONFIG (best: qkv 128x128 grid 768, out 128x64 grid 512). LDS passed in
// (hoisted) so template instantiations share the allocation.
// MODE 0: bf16 out per-head [B,H,S,HD]  (Q)
// MODE 1: fp32 out [M,N]                (final projection)
// MODE 3: bf16 K in MFMA A-fragment order
// MODE 4: bf16 V in MFMA B-fragment order
template <int MODE, int BMT, int BNT>
__device__ __forceinline__ void gemm_core(
    unsigned short* __restrict__ lsA,        // [2][BMT*32]
    unsigned short* __restrict__ lsB,        // [2][BNT*32]
    const unsigned short* __restrict__ A, const unsigned short* __restrict__ W,
    const float* __restrict__ bias, void* __restrict__ out, int bm, int bn) {
    constexpr int IT = BMT / 32, JT = BNT / 32;
    constexpr int ASTR = BMT * 32, BSTR = BNT * 32;
    const int t = threadIdx.x;
    const int lane = t & 63, l15 = lane & 15, quad = lane >> 4;
    const int wave = t >> 6;
    const int wm = (wave >> 1) * (BMT / 2), wn = (wave & 1) * (BNT / 2);

    // staging: lane t -> physical chunk (t&3) of row (t>>2); load logical chunk (t&3)^((t>>3)&3)
    const int cg = ((t & 3) ^ ((t >> 3) & 3)) * 8;
    const unsigned short* ga = A + (size_t)(bm + (t >> 2)) * 1024 + cg;
    const unsigned short* gb = W + (size_t)(bn + (t >> 2)) * 1024 + cg;

    f32x4 acc[IT][JT];
    for (int i = 0; i < IT; i++)
        for (int j = 0; j < JT; j++) acc[i][j] = (f32x4){0.f, 0.f, 0.f, 0.f};

    const int swz = (l15 >> 1) & 3;  // (row>>1)&3 for row = wX + i*16 + l15

    // stage K-slab 0 into buffer 0
    gll16(ga, &lsA[t * 8]);
    if (BMT == 128) gll16(ga + 64 * 1024, &lsA[2048 + t * 8]);
    gll16(gb, &lsB[t * 8]);
    if (BNT == 128) gll16(gb + 64 * 1024, &lsB[2048 + t * 8]);

    for (int it = 0; it < 32; it++) {
        const int cur = it & 1, nxt = cur ^ 1;
        __syncthreads();  // cur staging done (issued a full body ago); prev reads of nxt drained

        if (it < 31) {
            const int k0 = (it + 1) * 32;
            gll16(ga + k0, &lsA[nxt * ASTR + t * 8]);
            if (BMT == 128) gll16(ga + k0 + 64 * 1024, &lsA[nxt * ASTR + 2048 + t * 8]);
            gll16(gb + k0, &lsB[nxt * BSTR + t * 8]);
            if (BNT == 128) gll16(gb + k0 + 64 * 1024, &lsB[nxt * BSTR + 2048 + t * 8]);
        }

        bf16x8 af[IT], bfr[JT];
        for (int i = 0; i < IT; i++)
            af[i] = *(const bf16x8*)&lsA[cur * ASTR + (wm + i * 16 + l15) * 32 + ((quad ^ swz) * 8)];
        for (int j = 0; j < JT; j++)
            bfr[j] = *(const bf16x8*)&lsB[cur * BSTR + (wn + j * 16 + l15) * 32 + ((quad ^ swz) * 8)];
        for (int i = 0; i < IT; i++)
            for (int j = 0; j < JT; j++) acc[i][j] = MFMA16(af[i], bfr[j], acc[i][j]);
    }

    // epilogue: C row = quad*4+reg, col = l15 per 16x16 tile (m89-verified)
    for (int j = 0; j < JT; j++) {
        int n = bn + wn + j * 16 + l15;
        float bj = bias[n];
        for (int i = 0; i < IT; i++) {
            int m0 = bm + wm + i * 16 + quad * 4;
            int srow0 = m0 & 2047, bidx = m0 >> 11;
            if (MODE == 3) {
                size_t headb = ((size_t)bidx * HH + (n >> 6)) * (SS * HDD);
                size_t base = headb + (size_t)(srow0 >> 6) * 4096 +
                              (size_t)(((srow0 >> 4) & 3) * 8 + ((n & 63) >> 3)) * 128 + (n & 7);
                for (int rg = 0; rg < 4; rg++)
                    ((unsigned short*)out)[base + (size_t)((srow0 & 15) + rg) * 8] = f2bf(acc[i][j][rg] + bj);
            } else if (MODE == 4) {
                size_t headb = ((size_t)bidx * HH + (n >> 6)) * (SS * HDD);
                size_t addr = headb + (size_t)(srow0 >> 6) * 4096 + (size_t)((n & 63) >> 4) * 1024 +
                              (size_t)(((srow0 >> 5) & 1) * 4 + ((srow0 >> 3) & 3)) * 128 +
                              (size_t)(n & 15) * 8 + (srow0 & 7);
                float v0 = acc[i][j][0] + bj, v1 = acc[i][j][1] + bj;
                float v2 = acc[i][j][2] + bj, v3 = acc[i][j][3] + bj;
                uint2 w;
                w.x = (unsigned int)f2bf(v0) | ((unsigned int)f2bf(v1) << 16);
                w.y = (unsigned int)f2bf(v2) | ((unsigned int)f2bf(v3) << 16);
                *(uint2*)&((unsigned short*)out)[addr] = w;
            } else {
                for (int rg = 0; rg < 4; rg++) {
                    float val = acc[i][j][rg] + bj;
                    int m = m0 + rg;
                    if (MODE == 0) {
                        ((unsigned short*)out)[(((size_t)(m >> 11) * HH + (n >> 6)) * SS + (m & 2047)) * HDD + (n & 63)] = f2bf(val);
                    } else {
                        ((float*)out)[(size_t)m * 1024 + n] = val;
                    }
                }
            }
        }
    }
}

// grid 768 1-D (round-9 config); XCD swizzle: same-by blocks share an XCD
__global__ __launch_bounds__(256) void gemm_qkv(
    const unsigned short* __restrict__ xb,
    const unsigned short* __restrict__ wqb, const unsigned short* __restrict__ wkb,
    const unsigned short* __restrict__ wvb,
    const float* __restrict__ bq, const float* __restrict__ bk, const float* __restrict__ bv,
    unsigned short* qb, unsigned short* kb, unsigned short* vtb) {
    __shared__ unsigned short shA[2 * 4096];   // shared across all 3 instantiations
    __shared__ unsigned short shB[2 * 4096];
    const int blk = blockIdx.x;
    const int u = blk & 7, r = blk >> 3;
    const int by = u + 8 * (r & 3);          // 0..31
    const int rest = r >> 2;                 // 0..23
    const int bx = rest & 7, z = rest >> 3;  // 0..7, 0..2
    if (z == 0)      gemm_core<0, 128, 128>(shA, shB, xb, wqb, bq, qb,  by * 128, bx * 128);
    else if (z == 1) gemm_core<3, 128, 128>(shA, shB, xb, wkb, bk, kb,  by * 128, bx * 128);
    else             gemm_core<4, 128, 128>(shA, shB, xb, wvb, bv, vtb, by * 128, bx * 128);
}

// grid 512 1-D (round-9 config: 128x64 tiles)
__global__ __launch_bounds__(256) void gemm_out(
    const unsigned short* __restrict__ ob, const unsigned short* __restrict__ wob,
    const float* __restrict__ bo, float* __restrict__ out) {
    __shared__ unsigned short shA[2 * 4096];
    __shared__ unsigned short shB[2 * 2048];
    const int blk = blockIdx.x;
    const int u = blk & 7, r = blk >> 3;
    const int by = u + 8 * (r & 3);          // 0..31
    const int bx = r >> 2;                   // 0..15
    gemm_core<1, 128, 64>(shA, shB, ob, wob, bo, out, by * 128, bx * 64);
}

// ---------------- flash attention: INTRA-BLOCK SPLIT-K, 8 waves ----------------
// ROUND-13: K/V DOUBLE-BUFFERED in LDS, ONE barrier per iteration (gemm_core
// cadence). Round-2 showed the kernel is stall-bound, not pipe-bound: the old
// single-buffer loop issued the restage at iter end and immediately hit
// __syncthreads (s_waitcnt vmcnt(0)) -> full global latency exposed every iter.
// Now: [barrier] -> issue stage(nxt, kt+1) -> compute(cur); the stage has the
// whole body to land before the next barrier drains it. Barriers 2/iter -> 1.
// Kept from round-11/12: in-register P transpose (permlane32/16_swap, P never
// touches LDS, bank conflicts = 0). Denominator back to P.ones MFMA (4/iter on
// the 27%-utilized MFMA pipe) instead of per-lane truncated sums + butterfly
// (~64 VALU/iter on the ~50%-busy VALU pipe); identical numerics (exact f32
// sum of truncated bf16 P either way).
// LDS: K[2buf][2half][4096] + V same = 65536 B -> 2 blocks/CU (131072<160K).
__global__ __launch_bounds__(512, 4) void attn_fwd(
    const unsigned short* __restrict__ qb, const unsigned short* __restrict__ kb,
    const unsigned short* __restrict__ vtb, unsigned short* __restrict__ ob) {
    __shared__ unsigned short sh[32768];  // lsK[2][2][4096] | lsV[2][2][4096]; combine aliases (40960 B) fit
    unsigned short* lsK = sh;
    unsigned short* lsV = sh + 16384;
    const int t = threadIdx.x, lane = t & 63, l15 = lane & 15, quad = lane >> 4;
    const int wave = t >> 6;          // 0..7
    const int half = wave >> 2;       // key-half
    const int wq = wave & 3;          // q-wave within half
    const int tg = t & 255;           // thread index within half-group
    const int blk = blockIdx.x;
    const int u = blk & 7, r = blk >> 3;
    const int bh = u + 8 * (r & 3);   // 0..31: 4 heads per XCD
    const int qt = r >> 2;            // 0..15
    const size_t hoff = (size_t)bh * (SS * HDD);
    const float C = 0.125f * 1.44269504088896f;  // 1/sqrt(HD) * log2(e)

    // Q fragments in registers, pre-scaled by C (used as B-operand for S^T)
    bf16x8 qf[2][2];
    const int qrow = qt * 128 + wq * 32;
    for (int i = 0; i < 2; i++)
        for (int ks = 0; ks < 2; ks++) {
            bf16x8 raw = *(const bf16x8*)&qb[hoff + (size_t)(qrow + i * 16 + l15) * HDD + ks * 32 + quad * 8];
            unsigned short tmp[8];
            *(bf16x8*)tmp = raw;
            for (int j = 0; j < 8; j++) {
                float f = __builtin_bit_cast(float, (unsigned int)tmp[j] << 16);
                tmp[j] = f2bf(f * C);
            }
            qf[i][ks] = *(const bf16x8*)tmp;
        }

    unsigned short onesbuf[8];
    for (int j = 0; j < 8; j++) onesbuf[j] = 0x3F80;  // bf16 1.0
    const bf16x8 onesf = *(const bf16x8*)onesbuf;

    f32x4 lacc[2];                 // row-sums (denominator), C-layout rows
    f32x4 o[2][4];
    for (int i = 0; i < 2; i++) {
        lacc[i] = (f32x4){0.f, 0.f, 0.f, 0.f};
        for (int jh = 0; jh < 4; jh++) o[i][jh] = (f32x4){0.f, 0.f, 0.f, 0.f};
    }

    // this half's 16 fragment-order tiles
    const unsigned short* gk = kb + hoff + (size_t)half * 16 * 4096;
    const unsigned short* gv = vtb + hoff + (size_t)half * 16 * 4096;
    const int foff = quad * 128 + l15 * 8;  // fragment offset within a tile

    // stage(buf, tile): 4x gll16, 16B/lane over the 256-thread half-group
    auto stage = [&](int buf, int tile) {
        unsigned short* dk = lsK + buf * 8192 + half * 4096;
        unsigned short* dv = lsV + buf * 8192 + half * 4096;
        const unsigned short* sk = gk + tile * 4096;
        const unsigned short* sv = gv + tile * 4096;
        gll16(sk + tg * 8, dk + tg * 8);
        gll16(sk + 2048 + tg * 8, dk + 2048 + tg * 8);
        gll16(sv + tg * 8, dv + tg * 8);
        gll16(sv + 2048 + tg * 8, dv + 2048 + tg * 8);
    };

    stage(0, 0);

    for (int kt = 0; kt < 16; kt++) {
        const int cur = kt & 1;
        __syncthreads();  // stage(cur) landed (issued a full body ago); reads of nxt (iter kt-1) done

        if (kt < 15) stage(cur ^ 1, kt + 1);  // hidden under this whole body

        const unsigned short* myK = lsK + cur * 8192 + half * 4096;
        const unsigned short* myV = lsV + cur * 8192 + half * 4096;

        // K fragments from LDS (plain offsets, min-aliasing)
        bf16x8 kfr[4][2];
        for (int j = 0; j < 4; j++)
            for (int ks = 0; ks < 2; ks++)
                kfr[j][ks] = *(const bf16x8*)&myK[j * 1024 + ks * 512 + foff];

        // S^T = K (CQ)^T : tile(j,i) rows = keys j*16+quad*4+rg, col = qrow i*16+l15
        f32x4 st[2][4];
        for (int j = 0; j < 4; j++)
            for (int i = 0; i < 2; i++) {
                f32x4 z = (f32x4){0.f, 0.f, 0.f, 0.f};
                z = MFMA16(kfr[j][0], qf[i][0], z);
                z = MFMA16(kfr[j][1], qf[i][1], z);
                st[i][j] = z;
            }

        // P = exp2(S^T): pack to bf16 pairs, transpose in-register to PV
        // A-fragment order (permlane32+permlane16 swaps; no LDS).
        bf16x8 pf[2][2];
        for (int i = 0; i < 2; i++) {
            unsigned int W[4][2];
            for (int j = 0; j < 4; j++) {
                float e0 = __builtin_amdgcn_exp2f(st[i][j][0]);
                float e1 = __builtin_amdgcn_exp2f(st[i][j][1]);
                float e2 = __builtin_amdgcn_exp2f(st[i][j][2]);
                float e3 = __builtin_amdgcn_exp2f(st[i][j][3]);
                W[j][0] = (__builtin_bit_cast(unsigned int, e0) >> 16) |
                          (__builtin_bit_cast(unsigned int, e1) & 0xFFFF0000u);
                W[j][1] = (__builtin_bit_cast(unsigned int, e2) >> 16) |
                          (__builtin_bit_cast(unsigned int, e3) & 0xFFFF0000u);
            }

            unsigned int P0[4], P1[4];
            for (int h = 0; h < 2; h++) {
                unsigned int x = W[0][h], y = W[1][h];
                pl32swap(x, y);
                pl16swap(x, y);
                P0[h] = x; P0[2 + h] = y;
                unsigned int x2 = W[2][h], y2 = W[3][h];
                pl32swap(x2, y2);
                pl16swap(x2, y2);
                P1[h] = x2; P1[2 + h] = y2;
            }
            union { unsigned int u4[4]; bf16x8 v; } cv0, cv1;
            for (int p = 0; p < 4; p++) { cv0.u4[p] = P0[p]; cv1.u4[p] = P1[p]; }
            pf[i][0] = cv0.v;
            pf[i][1] = cv1.v;
        }

        // O += P V ; l += P . ones   (V fragments streamed from LDS)
        for (int jh = 0; jh < 4; jh++) {
            bf16x8 v0 = *(const bf16x8*)&myV[jh * 1024 + foff];
            bf16x8 v1 = *(const bf16x8*)&myV[jh * 1024 + 512 + foff];
            for (int i = 0; i < 2; i++) {
                o[i][jh] = MFMA16(pf[i][0], v0, o[i][jh]);
                o[i][jh] = MFMA16(pf[i][1], v1, o[i][jh]);
            }
        }
        for (int i = 0; i < 2; i++) {
            lacc[i] = MFMA16(pf[i][0], onesf, lacc[i]);
            lacc[i] = MFMA16(pf[i][1], onesf, lacc[i]);
        }
    }

    // ----- combine halves via LDS (fp32), then epilogue -----
    __syncthreads();  // all LDS reads done before alias overwrite
    float* cb = (float*)sh;           // N: [32 elems][4 wq][64 lanes], element-major (conflict-free)
    float* lb = cb + 8192;            // l: [8 elems][4 wq][64 lanes]
    const int lslot = wq * 64 + lane;
    if (half == 1) {
        for (int i = 0; i < 2; i++)
            for (int jh = 0; jh < 4; jh++)
                for (int rg = 0; rg < 4; rg++)
                    cb[(i * 16 + jh * 4 + rg) * 256 + lslot] = o[i][jh][rg];
        for (int i = 0; i < 2; i++)
            for (int rg = 0; rg < 4; rg++)
                lb[(i * 4 + rg) * 256 + lslot] = lacc[i][rg];
    }
    __syncthreads();
    if (half == 0) {
        const int b = bh >> 4, h = bh & 15;
        for (int i = 0; i < 2; i++)
            for (int rg = 0; rg < 4; rg++) {
                float inv = 1.f / (lacc[i][rg] + lb[(i * 4 + rg) * 256 + lslot]);
                int srow = qrow + i * 16 + quad * 4 + rg;
                size_t rowoff = ((size_t)b * SS + srow) * EE + h * 64;
                for (int jh = 0; jh < 4; jh++) {
                    float val = o[i][jh][rg] + cb[(i * 16 + jh * 4 + rg) * 256 + lslot];
                    ob[rowoff + jh * 16 + l15] = f2bf(val * inv);
                }
            }
    }
}

extern "C" void kernel_launch(void* const* d_in, const int* in_sizes, int n_in,
                              void* d_out, int out_size, void* d_ws, size_t ws_size,
                              hipStream_t stream) {
    const float* x  = (const float*)d_in[0];
    const float* wq = (const float*)d_in[1];
    const float* bq = (const float*)d_in[2];
    const float* wk = (const float*)d_in[3];
    const float* bk = (const float*)d_in[4];
    const float* wv = (const float*)d_in[5];
    const float* bv = (const float*)d_in[6];
    const float* wo = (const float*)d_in[7];
    const float* bo = (const float*)d_in[8];

    char* ws = (char*)d_ws;
    unsigned short* xb  = (unsigned short*)(ws + 0);          // 8 MB, reused as ob after qkv
    unsigned short* wqb = (unsigned short*)(ws + 8388608);    // 2 MB
    unsigned short* wkb = (unsigned short*)(ws + 10485760);
    unsigned short* wvb = (unsigned short*)(ws + 12582912);
    unsigned short* wob = (unsigned short*)(ws + 14680064);
    unsigned short* qb  = (unsigned short*)(ws + 16777216);   // 8 MB each
    unsigned short* kb  = (unsigned short*)(ws + 25165824);   // K in fragment order
    unsigned short* vtb = (unsigned short*)(ws + 33554432);   // V in fragment order
    unsigned short* ob  = xb;  // x no longer needed after qkv GEMM

    cvt_all<<<8192, 256, 0, stream>>>(x, wq, wk, wv, wo, xb, wqb, wkb, wvb, wob);
    gemm_qkv<<<768, 256, 0, stream>>>(xb, wqb, wkb, wvb, bq, bk, bv, qb, kb, vtb);
    attn_fwd<<<512, 512, 0, stream>>>(qb, kb, vtb, ob);
    gemm_out<<<512, 256, 0, stream>>>(ob, wob, bo, (float*)d_out);
}